// Round 5
// baseline (204.304 us; speedup 1.0000x reference)
//
#include <hip/hip_runtime.h>

typedef __attribute__((ext_vector_type(8))) short bf16x8;
typedef __attribute__((ext_vector_type(4))) float f32x4;
typedef unsigned short u16;
typedef unsigned int u32;

#define DEV static __device__ __forceinline__

// problem sizes (fixed by the reference)
#define CB 4
#define CN 2048
#define CD 1024
#define CM 8192   // CB*CN

DEV u16 f2bf(float f) {
  u32 u = __float_as_uint(f);
  u = (u + 0x7FFFu + ((u >> 16) & 1u)) >> 16;
  return (u16)u;
}
DEV float bf2f(u16 h) { return __uint_as_float(((u32)h) << 16); }

#define GLD16(gsrc, ldst)                                                        \
  __builtin_amdgcn_global_load_lds(                                              \
      (const __attribute__((address_space(1))) void*)(gsrc),                     \
      (__attribute__((address_space(3))) void*)(ldst), 16, 0, 0)

#define SBAR()  asm volatile("s_barrier" ::: "memory")
#define WAITL() asm volatile("s_waitcnt lgkmcnt(0)" ::: "memory")
#define WAITV2() asm volatile("s_waitcnt vmcnt(2)" ::: "memory")
#define WAITV0() asm volatile("s_waitcnt vmcnt(0)" ::: "memory")

// LDS half-tile = [128 rows][64 k] bf16 (16KB), XOR-swizzled:
//   byte ^= ((byte>>7)&7)<<4   (row&7 -> 16B-slot, involution)
DEV bf16x8 lds_read8(const short* half, int row, int kelem) {
  int b = row * 128 + kelem * 2;
  b ^= ((b >> 7) & 7) << 4;
  return *(const bf16x8*)((const char*)half + b);
}

DEV void stage_half(const u16* __restrict__ g, int ld, int row0, int kb,
                    short* lds_half, int tid) {
#pragma unroll
  for (int s = 0; s < 2; ++s) {
    const int c = tid + s * 512;                // 16B chunk 0..1023
    const int lo = (c ^ ((c >> 3) & 7)) & 7;    // intra-row source chunk
    GLD16(g + (size_t)(row0 + (c >> 3)) * ld + kb + lo * 8,
          (char*)lds_half + c * 16);
  }
}

// ---------------------------------------------------------------------------
// 256x256 8-phase core. 8 waves (2x4), wave tile 128x64, acc[8][4].
// LDS 128KB: per buffer A0@0, A1@8192, B0@16384, B1@24576 (shorts).
//
// READ-SET NOTE (race post-mortem R4): every phase's LDS reads span ALL four
// half-tile regions across the 8 waves (wr selects A-half, wc>>1 selects
// B-half). Invariant: tile t+1 must be FULLY landed before the end-of-tile-t
// barrier. Stage plan: ph1: B0,B1,A1(t+1)->nxt (6 loads; nxt's old data was
// fully consumed in tile t-1); ph4: A0(t+2)->cur (cur-A0 last read at ph3).
// Single counted wait at end-ph4: vmcnt(2) drains A0/B0/B1/A1(t+1) (3-4
// phases of latency cover each), keeps A0(t+2) in flight. Tail: vmcnt(0).
// ---------------------------------------------------------------------------
template <int MH, int NH>
DEV void mfma_quad(f32x4 (&acc)[8][4], const bf16x8 (&Af)[4][2],
                   const bf16x8 (&Bfh)[2][2]) {
#pragma unroll
  for (int mm = 0; mm < 4; ++mm)
#pragma unroll
    for (int nn = 0; nn < 2; ++nn)
#pragma unroll
      for (int ks = 0; ks < 2; ++ks)
        acc[MH * 4 + mm][NH * 2 + nn] = __builtin_amdgcn_mfma_f32_16x16x32_bf16(
            Af[mm][ks], Bfh[nn][ks], acc[MH * 4 + mm][NH * 2 + nn], 0, 0, 0);
}

DEV void gemm_core8(const u16* __restrict__ A, int lda,
                    const u16* __restrict__ Bt, int ldb,
                    int m0, int n0, int K, short* lds, f32x4 (&acc)[8][4])
{
  const int tid = threadIdx.x;
  const int lane = tid & 63;
  const int wid = tid >> 6;
  const int wr = wid >> 2, wc = wid & 3;
  const int lr = lane & 15, kg = lane >> 4;
  const int nt = K >> 6;

  short* buf0 = lds;
  short* buf1 = lds + 32768;

  // prologue: tile0 {A0,B0,B1,A1} + tile1 {A0}; drain tile0, keep A0(1) in flight
  stage_half(A,  lda, m0,       0, buf0,         tid);
  stage_half(Bt, ldb, n0,       0, buf0 + 16384, tid);
  stage_half(Bt, ldb, n0 + 128, 0, buf0 + 24576, tid);
  stage_half(A,  lda, m0 + 128, 0, buf0 + 8192,  tid);
  if (nt > 1) stage_half(A, lda, m0, 64, buf1, tid);
  WAITV2();
  SBAR();

  bf16x8 Af[4][2], Bf[2][2][2];

  for (int t = 0; t < nt; ++t) {
    short* cur = (t & 1) ? buf1 : buf0;
    short* nxt = (t & 1) ? buf0 : buf1;
    const short* aHalf = cur + wr * 8192;
    const short* bHalf = cur + 16384 + (wc >> 1) * 8192;
    const int bl0 = (wc & 1) * 64;
    const int kb1 = (t + 1) << 6, kb2 = (t + 2) << 6;

    // ---- phase 1: Q(0,0); read Af<-mh0 (8) + Bf[0] (4); stage B0,B1,A1(t+1)
#pragma unroll
    for (int m = 0; m < 4; ++m)
#pragma unroll
      for (int ks = 0; ks < 2; ++ks)
        Af[m][ks] = lds_read8(aHalf, m * 16 + lr, ks * 32 + kg * 8);
#pragma unroll
    for (int n = 0; n < 2; ++n)
#pragma unroll
      for (int ks = 0; ks < 2; ++ks)
        Bf[0][n][ks] = lds_read8(bHalf, bl0 + n * 16 + lr, ks * 32 + kg * 8);
    if (t + 1 < nt) {
      stage_half(Bt, ldb, n0,       kb1, nxt + 16384, tid);
      stage_half(Bt, ldb, n0 + 128, kb1, nxt + 24576, tid);
      stage_half(A,  lda, m0 + 128, kb1, nxt + 8192,  tid);
    }
    SBAR(); WAITL();
    __builtin_amdgcn_sched_barrier(0);
    __builtin_amdgcn_s_setprio(1);
    mfma_quad<0, 0>(acc, Af, Bf[0]);
    __builtin_amdgcn_s_setprio(0);
    SBAR();

    // ---- phase 2: Q(0,1); read Bf[1] (4)
#pragma unroll
    for (int n = 0; n < 2; ++n)
#pragma unroll
      for (int ks = 0; ks < 2; ++ks)
        Bf[1][n][ks] = lds_read8(bHalf, bl0 + 32 + n * 16 + lr, ks * 32 + kg * 8);
    SBAR(); WAITL();
    __builtin_amdgcn_sched_barrier(0);
    __builtin_amdgcn_s_setprio(1);
    mfma_quad<0, 1>(acc, Af, Bf[1]);
    __builtin_amdgcn_s_setprio(0);
    SBAR();

    // ---- phase 3: Q(1,1); read Af<-mh1 (8)
#pragma unroll
    for (int m = 0; m < 4; ++m)
#pragma unroll
      for (int ks = 0; ks < 2; ++ks)
        Af[m][ks] = lds_read8(aHalf, 64 + m * 16 + lr, ks * 32 + kg * 8);
    SBAR(); WAITL();
    __builtin_amdgcn_sched_barrier(0);
    __builtin_amdgcn_s_setprio(1);
    mfma_quad<1, 1>(acc, Af, Bf[1]);
    __builtin_amdgcn_s_setprio(0);
    SBAR();

    // ---- phase 4: Q(1,0); stage A0(t+2)->cur; single end-of-tile wait
    if (t + 2 < nt) stage_half(A, lda, m0, kb2, cur, tid);
    SBAR(); WAITL();
    __builtin_amdgcn_sched_barrier(0);
    __builtin_amdgcn_s_setprio(1);
    mfma_quad<1, 0>(acc, Af, Bf[0]);
    __builtin_amdgcn_s_setprio(0);
    if (t + 2 < nt) { WAITV2(); } else { WAITV0(); }
    SBAR();
  }
}

// ---------------------------------------------------------------------------
// 256x128 8-phase core. 8 waves (4x2), wave tile 64x64, acc[4][4].
// LDS 96KB: per buffer A0@0, A1@8192, B@16384 (shorts, 24576/buffer).
// Same invariant as gemm_core8 (ph1 reads parts of A0, A1 AND B across
// waves). Stage plan: ph1: A0,A1(t+1)->nxt (4 loads); ph3: B(t+2)->cur
// (cur-B last read at ph2). End-ph4: vmcnt(2) drains B(t+1),A0,A1(t+1)
// (3-5 phases cover), keeps B(t+2). Tail: vmcnt(0).
// ---------------------------------------------------------------------------
template <int MH, int NH>
DEV void mfma_oct(f32x4 (&acc)[4][4], const bf16x8 (&Af)[2][2],
                  const bf16x8 (&Bfh)[2][2]) {
#pragma unroll
  for (int mm = 0; mm < 2; ++mm)
#pragma unroll
    for (int nn = 0; nn < 2; ++nn)
#pragma unroll
      for (int ks = 0; ks < 2; ++ks)
        acc[MH * 2 + mm][NH * 2 + nn] = __builtin_amdgcn_mfma_f32_16x16x32_bf16(
            Af[mm][ks], Bfh[nn][ks], acc[MH * 2 + mm][NH * 2 + nn], 0, 0, 0);
}

DEV void gemm_core_n128(const u16* __restrict__ A, int lda,
                        const u16* __restrict__ Bt, int ldb,
                        int m0, int n0, int K, short* lds, f32x4 (&acc)[4][4])
{
  const int tid = threadIdx.x;
  const int lane = tid & 63;
  const int wid = tid >> 6;
  const int wr = wid >> 1, wc = wid & 1;   // 4x2 wave grid
  const int lr = lane & 15, kg = lane >> 4;
  const int nt = K >> 6;

  short* buf0 = lds;
  short* buf1 = lds + 24576;

  stage_half(Bt, ldb, n0,       0, buf0 + 16384, tid);
  stage_half(A,  lda, m0,       0, buf0,         tid);
  stage_half(A,  lda, m0 + 128, 0, buf0 + 8192,  tid);
  if (nt > 1) stage_half(Bt, ldb, n0, 64, buf1 + 16384, tid);
  WAITV2();
  SBAR();

  bf16x8 Af[2][2], Bf[2][2][2];

  for (int t = 0; t < nt; ++t) {
    short* cur = (t & 1) ? buf1 : buf0;
    short* nxt = (t & 1) ? buf0 : buf1;
    const short* aHalf = cur + (wr >> 1) * 8192;
    const short* bHalf = cur + 16384;
    const int ar0 = (wr & 1) * 64;
    const int bc0 = wc * 64;
    const int kb1 = (t + 1) << 6, kb2 = (t + 2) << 6;

    // ---- phase 1: (mh0,nh0); read Af[0..1] + Bf[0]; stage A0,A1(t+1)->nxt
#pragma unroll
    for (int m = 0; m < 2; ++m)
#pragma unroll
      for (int ks = 0; ks < 2; ++ks)
        Af[m][ks] = lds_read8(aHalf, ar0 + m * 16 + lr, ks * 32 + kg * 8);
#pragma unroll
    for (int n = 0; n < 2; ++n)
#pragma unroll
      for (int ks = 0; ks < 2; ++ks)
        Bf[0][n][ks] = lds_read8(bHalf, bc0 + n * 16 + lr, ks * 32 + kg * 8);
    if (t + 1 < nt) {
      stage_half(A, lda, m0,       kb1, nxt,        tid);
      stage_half(A, lda, m0 + 128, kb1, nxt + 8192, tid);
    }
    SBAR(); WAITL();
    __builtin_amdgcn_sched_barrier(0);
    __builtin_amdgcn_s_setprio(1);
    mfma_oct<0, 0>(acc, Af, Bf[0]);
    __builtin_amdgcn_s_setprio(0);
    SBAR();

    // ---- phase 2: (mh0,nh1); read Bf[1]
#pragma unroll
    for (int n = 0; n < 2; ++n)
#pragma unroll
      for (int ks = 0; ks < 2; ++ks)
        Bf[1][n][ks] = lds_read8(bHalf, bc0 + 32 + n * 16 + lr, ks * 32 + kg * 8);
    SBAR(); WAITL();
    __builtin_amdgcn_sched_barrier(0);
    __builtin_amdgcn_s_setprio(1);
    mfma_oct<0, 1>(acc, Af, Bf[1]);
    __builtin_amdgcn_s_setprio(0);
    SBAR();

    // ---- phase 3: (mh1,nh1); read Af[2..3]; stage B(t+2)->cur
#pragma unroll
    for (int m = 0; m < 2; ++m)
#pragma unroll
      for (int ks = 0; ks < 2; ++ks)
        Af[m][ks] = lds_read8(aHalf, ar0 + 32 + m * 16 + lr, ks * 32 + kg * 8);
    if (t + 2 < nt) stage_half(Bt, ldb, n0, kb2, cur + 16384, tid);
    SBAR(); WAITL();
    __builtin_amdgcn_sched_barrier(0);
    __builtin_amdgcn_s_setprio(1);
    mfma_oct<1, 1>(acc, Af, Bf[1]);
    __builtin_amdgcn_s_setprio(0);
    SBAR();

    // ---- phase 4: (mh1,nh0); pure MFMA + single end-of-tile wait
    __builtin_amdgcn_s_setprio(1);
    mfma_oct<1, 0>(acc, Af, Bf[0]);
    __builtin_amdgcn_s_setprio(0);
    if (t + 2 < nt) { WAITV2(); } else { WAITV0(); }
    SBAR();
  }
}

// ---------------------------------------------------------------------------
// elementwise f32 -> bf16, two tensors in one launch (z selects)
// ---------------------------------------------------------------------------
__global__ __launch_bounds__(256) void cvt_bf16_kernel(const float* __restrict__ in0,
                                                       u16* __restrict__ out0,
                                                       const float* __restrict__ in1,
                                                       u16* __restrict__ out1)
{
  const float* in = blockIdx.y ? in1 : in0;
  u16* out = blockIdx.y ? out1 : out0;
  const size_t i = ((size_t)blockIdx.x * 256 + threadIdx.x) * 4;
  const float4 v = *(const float4*)(in + i);
  u16 o[4] = {f2bf(v.x), f2bf(v.y), f2bf(v.z), f2bf(v.w)};
  *(ushort4*)(out + i) = *(ushort4*)o;
}

// W [1024][1024] f32 -> WT [n][k] bf16; z selects {Wq->WqT, Wk->WkvT, Wv->WkvT+1M}
__global__ __launch_bounds__(256) void transpose_w_kernel(
    const float* __restrict__ Wq, const float* __restrict__ Wk,
    const float* __restrict__ Wv, u16* __restrict__ WqT, u16* __restrict__ WkvT)
{
  __shared__ float tile[32][33];
  const int z = blockIdx.z;
  const float* W = (z == 0) ? Wq : ((z == 1) ? Wk : Wv);
  u16* WT = (z == 0) ? WqT : (WkvT + (z == 2 ? (size_t)CD * CD : 0));
  const int tx = threadIdx.x, ty = threadIdx.y;   // 32 x 8
  const int bx = blockIdx.x, by = blockIdx.y;
#pragma unroll
  for (int i = 0; i < 4; ++i)
    tile[ty + i * 8][tx] = W[(size_t)(by * 32 + ty + i * 8) * CD + bx * 32 + tx];
  __syncthreads();
#pragma unroll
  for (int i = 0; i < 4; ++i)
    WT[(size_t)(bx * 32 + ty + i * 8) * CD + by * 32 + tx] =
        f2bf(tile[tx][ty + i * 8]);
}

// V [CB*CN][CD] bf16 -> Vt [CB][CD][CN] bf16
__global__ __launch_bounds__(256) void transpose_v_kernel(const u16* __restrict__ V,
                                                          u16* __restrict__ Vt)
{
  __shared__ u16 tile[32][33];
  const int tx = threadIdx.x, ty = threadIdx.y;
  const int rt = blockIdx.x, dt = blockIdx.y, z = blockIdx.z;
#pragma unroll
  for (int i = 0; i < 4; ++i)
    tile[ty + i * 8][tx] =
        V[(size_t)(z * CN + rt * 32 + ty + i * 8) * CD + dt * 32 + tx];
  __syncthreads();
#pragma unroll
  for (int i = 0; i < 4; ++i)
    Vt[(size_t)z * CD * CN + (size_t)(dt * 32 + ty + i * 8) * CN + rt * 32 + tx] =
        tile[tx][ty + i * 8];
}

// vsum[b][d] = sum_r V[b*CN+r][d]
__global__ __launch_bounds__(256) void vsum_kernel(const u16* __restrict__ V,
                                                   float* __restrict__ vsum)
{
  const int c = blockIdx.x * 256 + threadIdx.x;
  const int b = blockIdx.y;
  const int r0 = blockIdx.z * 128;
  float s = 0.f;
#pragma unroll 8
  for (int r = 0; r < 128; ++r)
    s += bf2f(V[(size_t)(b * CN + r0 + r) * CD + c]);
  atomicAdd(&vsum[b * CD + c], s);
}

// ---------------------------------------------------------------------------
// fused K|V GEMM: x2b [8192][1024] x WkvT [2048][1024]^T -> K / V. grid 256.
// ---------------------------------------------------------------------------
__global__ __launch_bounds__(512, 2) void kv_kernel(
    const u16* __restrict__ x2b, const u16* __restrict__ WkvT,
    const float* __restrict__ bk, const float* __restrict__ bv,
    u16* __restrict__ Ko, u16* __restrict__ Vo)
{
  extern __shared__ char smem_raw[];
  short* lds = (short*)smem_raw;
  const int flat = blockIdx.y * 32 + blockIdx.x;      // nwg=256
  const int s = (flat & 7) * 32 + (flat >> 3);        // XCD swizzle
  const int bx = s & 31, by = s >> 5;
  const int m0 = bx * 256, n0 = by * 256;

  f32x4 acc[8][4] = {};
  gemm_core8(x2b, CD, WkvT, CD, m0, n0, CD, lds, acc);

  const int tid = threadIdx.x, lane = tid & 63, wid = tid >> 6;
  const int wr = wid >> 2, wc = wid & 3, lr = lane & 15, kg = lane >> 4;
  const bool isK = (n0 < CD);
  u16* Y = isK ? Ko : Vo;
  const float* bias = isK ? bk : bv;
  const int ncol0 = isK ? n0 : (n0 - CD);
#pragma unroll
  for (int mi = 0; mi < 8; ++mi)
#pragma unroll
    for (int ni = 0; ni < 4; ++ni) {
      const int col = ncol0 + wc * 64 + ni * 16 + lr;
      const float bcol = bias[col];
#pragma unroll
      for (int j = 0; j < 4; ++j) {
        const int row = m0 + wr * 128 + mi * 16 + kg * 4 + j;
        Y[(size_t)row * CD + col] = f2bf(acc[mi][ni][j] + bcol);
      }
    }
}

// ---------------------------------------------------------------------------
// Q GEMM: x1b x WqT, 256x128 tiles. grid 256.
// ---------------------------------------------------------------------------
__global__ __launch_bounds__(512, 2) void q_kernel(
    const u16* __restrict__ x1b, const u16* __restrict__ WqT,
    const float* __restrict__ bq, u16* __restrict__ Q)
{
  extern __shared__ char smem_raw[];
  short* lds = (short*)smem_raw;
  const int flat = blockIdx.y * 32 + blockIdx.x;      // nwg=256
  const int s = (flat & 7) * 32 + (flat >> 3);
  const int bx = s & 31, by = s >> 5;                 // 32 m-tiles, 8 n-tiles
  const int m0 = bx * 256, n0 = by * 128;

  f32x4 acc[4][4] = {};
  gemm_core_n128(x1b, CD, WqT, CD, m0, n0, CD, lds, acc);

  const int tid = threadIdx.x, lane = tid & 63, wid = tid >> 6;
  const int wr = wid >> 1, wc = wid & 1, lr = lane & 15, kg = lane >> 4;
#pragma unroll
  for (int mi = 0; mi < 4; ++mi)
#pragma unroll
    for (int ni = 0; ni < 4; ++ni) {
      const int col = n0 + wc * 64 + ni * 16 + lr;
      const float bcol = bq[col];
#pragma unroll
      for (int j = 0; j < 4; ++j) {
        const int row = m0 + wr * 64 + mi * 16 + kg * 4 + j;
        Q[(size_t)row * CD + col] = f2bf(acc[mi][ni][j] + bcol);
      }
    }
}

// ---------------------------------------------------------------------------
// P = exp(Q*K^T/32) (bf16), row sums l via atomics.  grid (8,8,4)
// ---------------------------------------------------------------------------
__global__ __launch_bounds__(512, 2) void scores_kernel(
    const u16* __restrict__ Q, const u16* __restrict__ Km,
    u16* __restrict__ P, float* __restrict__ lsum)
{
  extern __shared__ char smem_raw[];
  short* lds = (short*)smem_raw;
  const int flat = (blockIdx.z * 8 + blockIdx.y) * 8 + blockIdx.x;  // nwg=256
  const int s = (flat & 7) * 32 + (flat >> 3);
  const int bx = s & 7, by = (s >> 3) & 7, bz = s >> 6;
  const int m0 = bx * 256, n0 = by * 256;
  const u16* A  = Q  + (size_t)bz * CN * CD;
  const u16* Bt = Km + (size_t)bz * CN * CD;

  f32x4 acc[8][4] = {};
  gemm_core8(A, CD, Bt, CD, m0, n0, CD, lds, acc);

  const int tid = threadIdx.x, lane = tid & 63, wid = tid >> 6;
  const int wr = wid >> 2, wc = wid & 3, lr = lane & 15, kg = lane >> 4;
  u16* Pb = P + (size_t)bz * CN * CN;
  float* lb = lsum + (size_t)bz * CN;
  const float sc = 0.03125f * 1.4426950408889634f;
#pragma unroll
  for (int mi = 0; mi < 8; ++mi) {
    float rs[4] = {0.f, 0.f, 0.f, 0.f};
#pragma unroll
    for (int ni = 0; ni < 4; ++ni) {
      const int col = n0 + wc * 64 + ni * 16 + lr;
#pragma unroll
      for (int j = 0; j < 4; ++j) {
        const int row = m0 + wr * 128 + mi * 16 + kg * 4 + j;
        const float pv = exp2f(acc[mi][ni][j] * sc);
        Pb[(size_t)row * CN + col] = f2bf(pv);
        rs[j] += pv;
      }
    }
#pragma unroll
    for (int j = 0; j < 4; ++j) {
      float v = rs[j];
      v += __shfl_xor(v, 1);
      v += __shfl_xor(v, 2);
      v += __shfl_xor(v, 4);
      v += __shfl_xor(v, 8);
      if (lr == 0)
        atomicAdd(&lb[m0 + wr * 128 + mi * 16 + kg * 4 + j], v);
    }
  }
}

// ---------------------------------------------------------------------------
// out = (vsum - (P@V)/l) / (N-1)   (f32).  256x128 tiles, grid (8,8,4)=256.
// ---------------------------------------------------------------------------
__global__ __launch_bounds__(512, 2) void pv_kernel(
    const u16* __restrict__ P, const u16* __restrict__ Vt,
    const float* __restrict__ lsum, const float* __restrict__ vsum,
    float* __restrict__ out)
{
  extern __shared__ char smem_raw[];
  short* lds = (short*)smem_raw;
  const int flat = (blockIdx.z * 8 + blockIdx.y) * 8 + blockIdx.x;  // nwg=256
  const int s = (flat & 7) * 32 + (flat >> 3);
  const int bx = s & 7, by = (s >> 3) & 7, bz = s >> 6;
  const int m0 = bx * 256, n0 = by * 128;
  const u16* A  = P  + (size_t)bz * CN * CN;   // [2048][2048]
  const u16* Bt = Vt + (size_t)bz * CD * CN;   // [1024][2048]

  f32x4 acc[4][4] = {};
  gemm_core_n128(A, CN, Bt, CN, m0, n0, CN, lds, acc);

  const int tid = threadIdx.x, lane = tid & 63, wid = tid >> 6;
  const int wr = wid >> 1, wc = wid & 1, lr = lane & 15, kg = lane >> 4;
  const float inv_nm1 = 1.0f / (float)(CN - 1);
#pragma unroll
  for (int mi = 0; mi < 4; ++mi)
#pragma unroll
    for (int j = 0; j < 4; ++j) {
      const int row = m0 + wr * 64 + mi * 16 + kg * 4 + j;
      const float rl = 1.0f / lsum[(size_t)bz * CN + row];
#pragma unroll
      for (int ni = 0; ni < 4; ++ni) {
        const int col = n0 + wc * 64 + ni * 16 + lr;
        const float ctx = (vsum[bz * CD + col] - acc[mi][ni][j] * rl) * inv_nm1;
        out[(size_t)(bz * CN + row) * CD + col] = ctx;
      }
    }
}

// in-place LayerNorm + ReLU per row of 1024
__global__ __launch_bounds__(256) void ln_relu_kernel(float* __restrict__ io,
                                                      const float* __restrict__ gamma,
                                                      const float* __restrict__ beta)
{
  float* x = io + (size_t)blockIdx.x * CD;
  const int t = threadIdx.x;
  float4 v = ((const float4*)x)[t];
  float s = v.x + v.y + v.z + v.w;
  float q = v.x * v.x + v.y * v.y + v.z * v.z + v.w * v.w;
#pragma unroll
  for (int off = 1; off < 64; off <<= 1) {
    s += __shfl_xor(s, off);
    q += __shfl_xor(q, off);
  }
  __shared__ float ss[4], qq[4];
  const int w = t >> 6, lane = t & 63;
  if (lane == 0) { ss[w] = s; qq[w] = q; }
  __syncthreads();
  s = ss[0] + ss[1] + ss[2] + ss[3];
  q = qq[0] + qq[1] + qq[2] + qq[3];
  const float mean = s * (1.0f / CD);
  const float var  = q * (1.0f / CD) - mean * mean;
  const float rstd = rsqrtf(var + 1e-5f);
  const float4 g  = ((const float4*)gamma)[t];
  const float4 bb = ((const float4*)beta)[t];
  v.x = fmaxf(0.f, (v.x - mean) * rstd * g.x + bb.x);
  v.y = fmaxf(0.f, (v.y - mean) * rstd * g.y + bb.y);
  v.z = fmaxf(0.f, (v.z - mean) * rstd * g.z + bb.z);
  v.w = fmaxf(0.f, (v.w - mean) * rstd * g.w + bb.w);
  ((float4*)x)[t] = v;
}

// ---------------------------------------------------------------------------
extern "C" void kernel_launch(void* const* d_in, const int* in_sizes, int n_in,
                              void* d_out, int out_size, void* d_ws, size_t ws_size,
                              hipStream_t stream)
{
  (void)in_sizes; (void)n_in; (void)out_size; (void)ws_size;
  const float* x1    = (const float*)d_in[0];
  const float* x2    = (const float*)d_in[1];
  const float* Wq    = (const float*)d_in[2];
  const float* bq    = (const float*)d_in[3];
  const float* Wk    = (const float*)d_in[4];
  const float* bk    = (const float*)d_in[5];
  const float* Wv    = (const float*)d_in[6];
  const float* bv    = (const float*)d_in[7];
  const float* gamma = (const float*)d_in[8];
  const float* beta  = (const float*)d_in[9];
  float* out = (float*)d_out;

  const int LDS_BIG = 131072, LDS_MID = 98304;
  hipFuncSetAttribute((const void*)kv_kernel,
                      hipFuncAttributeMaxDynamicSharedMemorySize, LDS_BIG);
  hipFuncSetAttribute((const void*)scores_kernel,
                      hipFuncAttributeMaxDynamicSharedMemorySize, LDS_BIG);
  hipFuncSetAttribute((const void*)q_kernel,
                      hipFuncAttributeMaxDynamicSharedMemorySize, LDS_MID);
  hipFuncSetAttribute((const void*)pv_kernel,
                      hipFuncAttributeMaxDynamicSharedMemorySize, LDS_MID);

  char* p = (char*)d_ws;
  auto alloc = [&](size_t bytes) -> char* {
    char* r = p;
    p += (bytes + 255) & ~(size_t)255;
    return r;
  };
  u16* x1b   = (u16*)alloc((size_t)CM * CD * 2);
  u16* x2b   = (u16*)alloc((size_t)CM * CD * 2);
  u16* WqT   = (u16*)alloc((size_t)CD * CD * 2);
  u16* WkvT  = (u16*)alloc((size_t)2 * CD * CD * 2);
  u16* Qb    = (u16*)alloc((size_t)CM * CD * 2);
  u16* Kb    = (u16*)alloc((size_t)CM * CD * 2);
  u16* Vb    = (u16*)alloc((size_t)CM * CD * 2);
  u16* Vt    = (u16*)alloc((size_t)CM * CD * 2);
  u16* Pp    = (u16*)alloc((size_t)CB * CN * CN * 2);
  float* ls  = (float*)alloc((size_t)CB * CN * 4);
  float* vs  = (float*)alloc((size_t)CB * CD * 4);

  hipMemsetAsync(ls, 0, (size_t)CB * CN * 4, stream);
  hipMemsetAsync(vs, 0, (size_t)CB * CD * 4, stream);

  // f32 -> bf16 inputs (one launch)
  {
    dim3 g(CM * CD / 1024, 2);
    cvt_bf16_kernel<<<g, 256, 0, stream>>>(x1, x1b, x2, x2b);
  }

  // W transposes (one launch)
  {
    dim3 g(32, 32, 3), blk(32, 8);
    transpose_w_kernel<<<g, blk, 0, stream>>>(Wq, Wk, Wv, WqT, WkvT);
  }

  // fused K|V projection (256 blocks)
  {
    dim3 g(32, 8);
    kv_kernel<<<g, 512, LDS_BIG, stream>>>(x2b, WkvT, bk, bv, Kb, Vb);
  }

  // V transpose + column sums
  {
    dim3 g(CN / 32, CD / 32, CB), blk(32, 8);
    transpose_v_kernel<<<g, blk, 0, stream>>>(Vb, Vt);
  }
  {
    dim3 g(CD / 256, CB, CN / 128);
    vsum_kernel<<<g, 256, 0, stream>>>(Vb, vs);
  }

  // Q projection (256 blocks, 256x128 tiles)
  {
    dim3 g(32, 8);
    q_kernel<<<g, 512, LDS_MID, stream>>>(x1b, WqT, bq, Qb);
  }

  // P = exp(QK^T/32), l = rowsum(P)
  {
    dim3 g(8, 8, CB);
    scores_kernel<<<g, 512, LDS_BIG, stream>>>(Qb, Kb, Pp, ls);
  }

  // out = (vsum - P@V / l) / (N-1)   (256 blocks, 256x128 tiles)
  {
    dim3 g(8, 8, CB);
    pv_kernel<<<g, 512, LDS_MID, stream>>>(Pp, Vt, ls, vs, out);
  }

  // LayerNorm + ReLU in place
  ln_relu_kernel<<<CM, 256, 0, stream>>>(out, gamma, beta);
}

// Round 6
// 190.316 us; speedup vs baseline: 1.0735x; 1.0735x over previous
//
#include <hip/hip_runtime.h>

typedef __attribute__((ext_vector_type(8))) short bf16x8;
typedef __attribute__((ext_vector_type(4))) float f32x4;
typedef unsigned short u16;
typedef unsigned int u32;

#define DEV static __device__ __forceinline__

// problem sizes (fixed by the reference)
#define CB 4
#define CN 2048
#define CD 1024
#define CM 8192   // CB*CN

DEV u16 f2bf(float f) {
  u32 u = __float_as_uint(f);
  u = (u + 0x7FFFu + ((u >> 16) & 1u)) >> 16;
  return (u16)u;
}
DEV float bf2f(u16 h) { return __uint_as_float(((u32)h) << 16); }

#define GLD16(gsrc, ldst)                                                        \
  __builtin_amdgcn_global_load_lds(                                              \
      (const __attribute__((address_space(1))) void*)(gsrc),                     \
      (__attribute__((address_space(3))) void*)(ldst), 16, 0, 0)

#define SBAR()  asm volatile("s_barrier" ::: "memory")
#define WAITL() asm volatile("s_waitcnt lgkmcnt(0)" ::: "memory")
#define WAITV0() asm volatile("s_waitcnt vmcnt(0)" ::: "memory")

// LDS half-tile = [128 rows][64 k] bf16 (16KB), XOR-swizzled:
//   byte ^= ((byte>>7)&7)<<4   (row&7 -> 16B-slot, involution)
DEV bf16x8 lds_read8(const short* half, int row, int kelem) {
  int b = row * 128 + kelem * 2;
  b ^= ((b >> 7) & 7) << 4;
  return *(const bf16x8*)((const char*)half + b);
}

DEV void stage_half(const u16* __restrict__ g, int ld, int row0, int kb,
                    short* lds_half, int tid) {
#pragma unroll
  for (int s = 0; s < 2; ++s) {
    const int c = tid + s * 512;                // 16B chunk 0..1023
    const int lo = (c ^ ((c >> 3) & 7)) & 7;    // intra-row source chunk
    GLD16(g + (size_t)(row0 + (c >> 3)) * ld + kb + lo * 8,
          (char*)lds_half + c * 16);
  }
}

// ---------------------------------------------------------------------------
// 256x256 single-barrier core. 8 waves (2x4), wave tile 128x64, acc[8][4].
// LDS 128KB: per buffer A0@0, A1@8192, B0@16384, B1@24576 (shorts).
//
// R6 restructure: within a K-tile, cur is read-only and nxt is never read,
// so NO intra-tile barriers are needed. Per tile: issue ALL 8 next-tile
// gloads -> nxt; ds_reads (compiler inserts counted lgkmcnt before MFMA
// uses); 4 MFMA clusters; vmcnt(0) + s_barrier. LDS-read pipe now overlaps
// the MFMA pipe instead of being serialized by per-phase barrier pairs.
// Race ledger: stages only target nxt (unread in tile t); end-of-tile
// vmcnt(0) (per-wave drains its own share of every half) + barrier
// guarantees tile t+1 fully landed before any wave reads it.
// ---------------------------------------------------------------------------
template <int MH, int NH>
DEV void mfma_quad(f32x4 (&acc)[8][4], const bf16x8 (&Af)[4][2],
                   const bf16x8 (&Bfh)[2][2]) {
#pragma unroll
  for (int mm = 0; mm < 4; ++mm)
#pragma unroll
    for (int nn = 0; nn < 2; ++nn)
#pragma unroll
      for (int ks = 0; ks < 2; ++ks)
        acc[MH * 4 + mm][NH * 2 + nn] = __builtin_amdgcn_mfma_f32_16x16x32_bf16(
            Af[mm][ks], Bfh[nn][ks], acc[MH * 4 + mm][NH * 2 + nn], 0, 0, 0);
}

DEV void gemm_core8(const u16* __restrict__ A, int lda,
                    const u16* __restrict__ Bt, int ldb,
                    int m0, int n0, int K, short* lds, f32x4 (&acc)[8][4])
{
  const int tid = threadIdx.x;
  const int lane = tid & 63;
  const int wid = tid >> 6;
  const int wr = wid >> 2, wc = wid & 3;
  const int lr = lane & 15, kg = lane >> 4;
  const int nt = K >> 6;

  short* buf0 = lds;
  short* buf1 = lds + 32768;

  // prologue: stage tile0 into buf0, drain, barrier
  stage_half(A,  lda, m0,       0, buf0,         tid);
  stage_half(A,  lda, m0 + 128, 0, buf0 + 8192,  tid);
  stage_half(Bt, ldb, n0,       0, buf0 + 16384, tid);
  stage_half(Bt, ldb, n0 + 128, 0, buf0 + 24576, tid);
  WAITV0();
  SBAR();

  bf16x8 Af[4][2], Bf[2][2][2];

  for (int t = 0; t < nt; ++t) {
    short* cur = (t & 1) ? buf1 : buf0;
    short* nxt = (t & 1) ? buf0 : buf1;
    const short* aHalf = cur + wr * 8192;
    const short* bHalf = cur + 16384 + (wc >> 1) * 8192;
    const int bl0 = (wc & 1) * 64;
    const int kb1 = (t + 1) << 6;

    // issue next-tile stages early (8 gloads; full-tile latency cover)
    if (t + 1 < nt) {
      stage_half(A,  lda, m0,       kb1, nxt,         tid);
      stage_half(A,  lda, m0 + 128, kb1, nxt + 8192,  tid);
      stage_half(Bt, ldb, n0,       kb1, nxt + 16384, tid);
      stage_half(Bt, ldb, n0 + 128, kb1, nxt + 24576, tid);
    }

    // reads: mh0 A-frags (8) + both B-frag sets (8)
#pragma unroll
    for (int m = 0; m < 4; ++m)
#pragma unroll
      for (int ks = 0; ks < 2; ++ks)
        Af[m][ks] = lds_read8(aHalf, m * 16 + lr, ks * 32 + kg * 8);
#pragma unroll
    for (int n = 0; n < 2; ++n)
#pragma unroll
      for (int ks = 0; ks < 2; ++ks) {
        Bf[0][n][ks] = lds_read8(bHalf, bl0 + n * 16 + lr, ks * 32 + kg * 8);
        Bf[1][n][ks] = lds_read8(bHalf, bl0 + 32 + n * 16 + lr, ks * 32 + kg * 8);
      }

    __builtin_amdgcn_s_setprio(1);
    mfma_quad<0, 0>(acc, Af, Bf[0]);
    mfma_quad<0, 1>(acc, Af, Bf[1]);
    __builtin_amdgcn_s_setprio(0);

    // reads: mh1 A-frags (8), overwriting Af
#pragma unroll
    for (int m = 0; m < 4; ++m)
#pragma unroll
      for (int ks = 0; ks < 2; ++ks)
        Af[m][ks] = lds_read8(aHalf, 64 + m * 16 + lr, ks * 32 + kg * 8);

    __builtin_amdgcn_s_setprio(1);
    mfma_quad<1, 1>(acc, Af, Bf[1]);
    mfma_quad<1, 0>(acc, Af, Bf[0]);
    __builtin_amdgcn_s_setprio(0);

    WAITV0();
    SBAR();
  }
}

// ---------------------------------------------------------------------------
// 256x128 single-barrier core. 8 waves (4x2), wave tile 64x64, acc[4][4].
// LDS 96KB: per buffer A0@0, A1@8192, B@16384 (shorts, 24576/buffer).
// Same single-barrier protocol as gemm_core8.
// ---------------------------------------------------------------------------
template <int MH, int NH>
DEV void mfma_oct(f32x4 (&acc)[4][4], const bf16x8 (&Af)[2][2],
                  const bf16x8 (&Bfh)[2][2]) {
#pragma unroll
  for (int mm = 0; mm < 2; ++mm)
#pragma unroll
    for (int nn = 0; nn < 2; ++nn)
#pragma unroll
      for (int ks = 0; ks < 2; ++ks)
        acc[MH * 2 + mm][NH * 2 + nn] = __builtin_amdgcn_mfma_f32_16x16x32_bf16(
            Af[mm][ks], Bfh[nn][ks], acc[MH * 2 + mm][NH * 2 + nn], 0, 0, 0);
}

DEV void gemm_core_n128(const u16* __restrict__ A, int lda,
                        const u16* __restrict__ Bt, int ldb,
                        int m0, int n0, int K, short* lds, f32x4 (&acc)[4][4])
{
  const int tid = threadIdx.x;
  const int lane = tid & 63;
  const int wid = tid >> 6;
  const int wr = wid >> 1, wc = wid & 1;   // 4x2 wave grid
  const int lr = lane & 15, kg = lane >> 4;
  const int nt = K >> 6;

  short* buf0 = lds;
  short* buf1 = lds + 24576;

  stage_half(A,  lda, m0,       0, buf0,         tid);
  stage_half(A,  lda, m0 + 128, 0, buf0 + 8192,  tid);
  stage_half(Bt, ldb, n0,       0, buf0 + 16384, tid);
  WAITV0();
  SBAR();

  bf16x8 AfA[2][2], AfB[2][2], Bf[2][2][2];

  for (int t = 0; t < nt; ++t) {
    short* cur = (t & 1) ? buf1 : buf0;
    short* nxt = (t & 1) ? buf0 : buf1;
    const short* aHalf = cur + (wr >> 1) * 8192;
    const short* bHalf = cur + 16384;
    const int ar0 = (wr & 1) * 64;
    const int bc0 = wc * 64;
    const int kb1 = (t + 1) << 6;

    if (t + 1 < nt) {
      stage_half(A,  lda, m0,       kb1, nxt,         tid);
      stage_half(A,  lda, m0 + 128, kb1, nxt + 8192,  tid);
      stage_half(Bt, ldb, n0,       kb1, nxt + 16384, tid);
    }

    // all 16 frag reads upfront (64 VGPR)
#pragma unroll
    for (int m = 0; m < 2; ++m)
#pragma unroll
      for (int ks = 0; ks < 2; ++ks) {
        AfA[m][ks] = lds_read8(aHalf, ar0 + m * 16 + lr, ks * 32 + kg * 8);
        AfB[m][ks] = lds_read8(aHalf, ar0 + 32 + m * 16 + lr, ks * 32 + kg * 8);
      }
#pragma unroll
    for (int n = 0; n < 2; ++n)
#pragma unroll
      for (int ks = 0; ks < 2; ++ks) {
        Bf[0][n][ks] = lds_read8(bHalf, bc0 + n * 16 + lr, ks * 32 + kg * 8);
        Bf[1][n][ks] = lds_read8(bHalf, bc0 + 32 + n * 16 + lr, ks * 32 + kg * 8);
      }

    __builtin_amdgcn_s_setprio(1);
    mfma_oct<0, 0>(acc, AfA, Bf[0]);
    mfma_oct<0, 1>(acc, AfA, Bf[1]);
    mfma_oct<1, 1>(acc, AfB, Bf[1]);
    mfma_oct<1, 0>(acc, AfB, Bf[0]);
    __builtin_amdgcn_s_setprio(0);

    WAITV0();
    SBAR();
  }
}

// ---------------------------------------------------------------------------
// elementwise f32 -> bf16, two tensors in one launch (z selects)
// ---------------------------------------------------------------------------
__global__ __launch_bounds__(256) void cvt_bf16_kernel(const float* __restrict__ in0,
                                                       u16* __restrict__ out0,
                                                       const float* __restrict__ in1,
                                                       u16* __restrict__ out1)
{
  const float* in = blockIdx.y ? in1 : in0;
  u16* out = blockIdx.y ? out1 : out0;
  const size_t i = ((size_t)blockIdx.x * 256 + threadIdx.x) * 4;
  const float4 v = *(const float4*)(in + i);
  u16 o[4] = {f2bf(v.x), f2bf(v.y), f2bf(v.z), f2bf(v.w)};
  *(ushort4*)(out + i) = *(ushort4*)o;
}

// W [1024][1024] f32 -> WT [n][k] bf16; z selects {Wq->WqT, Wk->WkvT, Wv->WkvT+1M}
__global__ __launch_bounds__(256) void transpose_w_kernel(
    const float* __restrict__ Wq, const float* __restrict__ Wk,
    const float* __restrict__ Wv, u16* __restrict__ WqT, u16* __restrict__ WkvT)
{
  __shared__ float tile[32][33];
  const int z = blockIdx.z;
  const float* W = (z == 0) ? Wq : ((z == 1) ? Wk : Wv);
  u16* WT = (z == 0) ? WqT : (WkvT + (z == 2 ? (size_t)CD * CD : 0));
  const int tx = threadIdx.x, ty = threadIdx.y;   // 32 x 8
  const int bx = blockIdx.x, by = blockIdx.y;
#pragma unroll
  for (int i = 0; i < 4; ++i)
    tile[ty + i * 8][tx] = W[(size_t)(by * 32 + ty + i * 8) * CD + bx * 32 + tx];
  __syncthreads();
#pragma unroll
  for (int i = 0; i < 4; ++i)
    WT[(size_t)(bx * 32 + ty + i * 8) * CD + by * 32 + tx] =
        f2bf(tile[tx][ty + i * 8]);
}

// ---------------------------------------------------------------------------
// fused K|V GEMM: x2b [8192][1024] x WkvT [2048][1024]^T. grid 256.
// K-blocks (n0<CD): write K row-major. V-blocks: write Vt[b][d][n] via LDS
// transpose (2 passes, padded stride 264) + vsum partials via atomics.
// V row-major is never materialized (transpose_v + vsum kernels deleted).
// ---------------------------------------------------------------------------
__global__ __launch_bounds__(512, 2) void kv_kernel(
    const u16* __restrict__ x2b, const u16* __restrict__ WkvT,
    const float* __restrict__ bk, const float* __restrict__ bv,
    u16* __restrict__ Ko, u16* __restrict__ Vt, float* __restrict__ vsum)
{
  extern __shared__ char smem_raw[];
  short* lds = (short*)smem_raw;
  const int flat = blockIdx.y * 32 + blockIdx.x;      // nwg=256
  const int s = (flat & 7) * 32 + (flat >> 3);        // XCD swizzle
  const int bx = s & 31, by = s >> 5;
  const int m0 = bx * 256, n0 = by * 256;

  f32x4 acc[8][4] = {};
  gemm_core8(x2b, CD, WkvT, CD, m0, n0, CD, lds, acc);

  const int tid = threadIdx.x, lane = tid & 63, wid = tid >> 6;
  const int wr = wid >> 2, wc = wid & 3, lr = lane & 15, kg = lane >> 4;
  const bool isK = (n0 < CD);

  if (isK) {
#pragma unroll
    for (int mi = 0; mi < 8; ++mi)
#pragma unroll
      for (int ni = 0; ni < 4; ++ni) {
        const int col = n0 + wc * 64 + ni * 16 + lr;
        const float bcol = bk[col];
#pragma unroll
        for (int j = 0; j < 4; ++j) {
          const int row = m0 + wr * 128 + mi * 16 + kg * 4 + j;
          Ko[(size_t)row * CD + col] = f2bf(acc[mi][ni][j] + bcol);
        }
      }
  } else {
    const int c0 = n0 - CD;              // d-offset of this 256-col tile
    const int b = m0 >> 11;              // batch
    const int nwb = m0 & (CN - 1);       // n-offset within batch
    u16* ldsT = (u16*)smem_raw;          // [128][264] u16 = 67.6KB
    const int myp = wc >> 1;

    // vsum partials (bias included: wave covers 128 rows -> +128*bv[col])
#pragma unroll
    for (int ni = 0; ni < 4; ++ni) {
      const int col = c0 + wc * 64 + ni * 16 + lr;
      float sv = 128.0f * bv[col];
#pragma unroll
      for (int mi = 0; mi < 8; ++mi)
#pragma unroll
        for (int j = 0; j < 4; ++j)
          sv += acc[mi][ni][j];
      sv += __shfl_xor(sv, 16);
      sv += __shfl_xor(sv, 32);
      if (lane < 16) atomicAdd(&vsum[b * CD + col], sv);
    }

    // transpose via LDS, two 128-col passes
    for (int pass = 0; pass < 2; ++pass) {
      if (myp == pass) {
#pragma unroll
        for (int ni = 0; ni < 4; ++ni) {
          const int cl = (wc & 1) * 64 + ni * 16 + lr;   // 0..127
          const float bcol = bv[c0 + pass * 128 + cl];
#pragma unroll
          for (int mi = 0; mi < 8; ++mi)
#pragma unroll
            for (int j = 0; j < 4; ++j) {
              const int row = wr * 128 + mi * 16 + kg * 4 + j;  // 0..255
              ldsT[cl * 264 + row] = f2bf(acc[mi][ni][j] + bcol);
            }
        }
      }
      WAITL();
      SBAR();
      // coalesced copy-out: 128 d x 256 n bf16
#pragma unroll
      for (int i = 0; i < 8; ++i) {
        const int c = tid + i * 512;     // 0..4095
        const int dl = c >> 5;           // 0..127
        const int nk = c & 31;           // 0..31 (8-short chunks)
        bf16x8 vv = *(const bf16x8*)(ldsT + dl * 264 + nk * 8);
        *(bf16x8*)(Vt + ((size_t)b * CD + c0 + pass * 128 + dl) * CN +
                   nwb + nk * 8) = vv;
      }
      SBAR();
    }
  }
}

// ---------------------------------------------------------------------------
// Q GEMM: x1b x WqT, 256x128 tiles. grid 256.
// ---------------------------------------------------------------------------
__global__ __launch_bounds__(512, 2) void q_kernel(
    const u16* __restrict__ x1b, const u16* __restrict__ WqT,
    const float* __restrict__ bq, u16* __restrict__ Q)
{
  extern __shared__ char smem_raw[];
  short* lds = (short*)smem_raw;
  const int flat = blockIdx.y * 32 + blockIdx.x;      // nwg=256
  const int s = (flat & 7) * 32 + (flat >> 3);
  const int bx = s & 31, by = s >> 5;                 // 32 m-tiles, 8 n-tiles
  const int m0 = bx * 256, n0 = by * 128;

  f32x4 acc[4][4] = {};
  gemm_core_n128(x1b, CD, WqT, CD, m0, n0, CD, lds, acc);

  const int tid = threadIdx.x, lane = tid & 63, wid = tid >> 6;
  const int wr = wid >> 1, wc = wid & 1, lr = lane & 15, kg = lane >> 4;
#pragma unroll
  for (int mi = 0; mi < 4; ++mi)
#pragma unroll
    for (int ni = 0; ni < 4; ++ni) {
      const int col = n0 + wc * 64 + ni * 16 + lr;
      const float bcol = bq[col];
#pragma unroll
      for (int j = 0; j < 4; ++j) {
        const int row = m0 + wr * 64 + mi * 16 + kg * 4 + j;
        Q[(size_t)row * CD + col] = f2bf(acc[mi][ni][j] + bcol);
      }
    }
}

// ---------------------------------------------------------------------------
// P = exp(Q*K^T/32) (bf16), row sums l via atomics.  grid (8,8,4)
// ---------------------------------------------------------------------------
__global__ __launch_bounds__(512, 2) void scores_kernel(
    const u16* __restrict__ Q, const u16* __restrict__ Km,
    u16* __restrict__ P, float* __restrict__ lsum)
{
  extern __shared__ char smem_raw[];
  short* lds = (short*)smem_raw;
  const int flat = (blockIdx.z * 8 + blockIdx.y) * 8 + blockIdx.x;  // nwg=256
  const int s = (flat & 7) * 32 + (flat >> 3);
  const int bx = s & 7, by = (s >> 3) & 7, bz = s >> 6;
  const int m0 = bx * 256, n0 = by * 256;
  const u16* A  = Q  + (size_t)bz * CN * CD;
  const u16* Bt = Km + (size_t)bz * CN * CD;

  f32x4 acc[8][4] = {};
  gemm_core8(A, CD, Bt, CD, m0, n0, CD, lds, acc);

  const int tid = threadIdx.x, lane = tid & 63, wid = tid >> 6;
  const int wr = wid >> 2, wc = wid & 3, lr = lane & 15, kg = lane >> 4;
  u16* Pb = P + (size_t)bz * CN * CN;
  float* lb = lsum + (size_t)bz * CN;
  const float sc = 0.03125f * 1.4426950408889634f;
#pragma unroll
  for (int mi = 0; mi < 8; ++mi) {
    float rs[4] = {0.f, 0.f, 0.f, 0.f};
#pragma unroll
    for (int ni = 0; ni < 4; ++ni) {
      const int col = n0 + wc * 64 + ni * 16 + lr;
#pragma unroll
      for (int j = 0; j < 4; ++j) {
        const int row = m0 + wr * 128 + mi * 16 + kg * 4 + j;
        const float pv = exp2f(acc[mi][ni][j] * sc);
        Pb[(size_t)row * CN + col] = f2bf(pv);
        rs[j] += pv;
      }
    }
#pragma unroll
    for (int j = 0; j < 4; ++j) {
      float v = rs[j];
      v += __shfl_xor(v, 1);
      v += __shfl_xor(v, 2);
      v += __shfl_xor(v, 4);
      v += __shfl_xor(v, 8);
      if (lr == 0)
        atomicAdd(&lb[m0 + wr * 128 + mi * 16 + kg * 4 + j], v);
    }
  }
}

// ---------------------------------------------------------------------------
// out = (vsum - (P@V)/l) / (N-1)   (f32).  256x128 tiles, grid (8,8,4)=256.
// ---------------------------------------------------------------------------
__global__ __launch_bounds__(512, 2) void pv_kernel(
    const u16* __restrict__ P, const u16* __restrict__ Vt,
    const float* __restrict__ lsum, const float* __restrict__ vsum,
    float* __restrict__ out)
{
  extern __shared__ char smem_raw[];
  short* lds = (short*)smem_raw;
  const int flat = (blockIdx.z * 8 + blockIdx.y) * 8 + blockIdx.x;  // nwg=256
  const int s = (flat & 7) * 32 + (flat >> 3);
  const int bx = s & 7, by = (s >> 3) & 7, bz = s >> 6;
  const int m0 = bx * 256, n0 = by * 128;
  const u16* A  = P  + (size_t)bz * CN * CN;   // [2048][2048]
  const u16* Bt = Vt + (size_t)bz * CD * CN;   // [1024][2048]

  f32x4 acc[4][4] = {};
  gemm_core_n128(A, CN, Bt, CN, m0, n0, CN, lds, acc);

  const int tid = threadIdx.x, lane = tid & 63, wid = tid >> 6;
  const int wr = wid >> 1, wc = wid & 1, lr = lane & 15, kg = lane >> 4;
  const float inv_nm1 = 1.0f / (float)(CN - 1);
#pragma unroll
  for (int mi = 0; mi < 4; ++mi)
#pragma unroll
    for (int j = 0; j < 4; ++j) {
      const int row = m0 + wr * 64 + mi * 16 + kg * 4 + j;
      const float rl = 1.0f / lsum[(size_t)bz * CN + row];
#pragma unroll
      for (int ni = 0; ni < 4; ++ni) {
        const int col = n0 + wc * 64 + ni * 16 + lr;
        const float ctx = (vsum[bz * CD + col] - acc[mi][ni][j] * rl) * inv_nm1;
        out[(size_t)(bz * CN + row) * CD + col] = ctx;
      }
    }
}

// in-place LayerNorm + ReLU per row of 1024
__global__ __launch_bounds__(256) void ln_relu_kernel(float* __restrict__ io,
                                                      const float* __restrict__ gamma,
                                                      const float* __restrict__ beta)
{
  float* x = io + (size_t)blockIdx.x * CD;
  const int t = threadIdx.x;
  float4 v = ((const float4*)x)[t];
  float s = v.x + v.y + v.z + v.w;
  float q = v.x * v.x + v.y * v.y + v.z * v.z + v.w * v.w;
#pragma unroll
  for (int off = 1; off < 64; off <<= 1) {
    s += __shfl_xor(s, off);
    q += __shfl_xor(q, off);
  }
  __shared__ float ss[4], qq[4];
  const int w = t >> 6, lane = t & 63;
  if (lane == 0) { ss[w] = s; qq[w] = q; }
  __syncthreads();
  s = ss[0] + ss[1] + ss[2] + ss[3];
  q = qq[0] + qq[1] + qq[2] + qq[3];
  const float mean = s * (1.0f / CD);
  const float var  = q * (1.0f / CD) - mean * mean;
  const float rstd = rsqrtf(var + 1e-5f);
  const float4 g  = ((const float4*)gamma)[t];
  const float4 bb = ((const float4*)beta)[t];
  v.x = fmaxf(0.f, (v.x - mean) * rstd * g.x + bb.x);
  v.y = fmaxf(0.f, (v.y - mean) * rstd * g.y + bb.y);
  v.z = fmaxf(0.f, (v.z - mean) * rstd * g.z + bb.z);
  v.w = fmaxf(0.f, (v.w - mean) * rstd * g.w + bb.w);
  ((float4*)x)[t] = v;
}

// ---------------------------------------------------------------------------
extern "C" void kernel_launch(void* const* d_in, const int* in_sizes, int n_in,
                              void* d_out, int out_size, void* d_ws, size_t ws_size,
                              hipStream_t stream)
{
  (void)in_sizes; (void)n_in; (void)out_size; (void)ws_size;
  const float* x1    = (const float*)d_in[0];
  const float* x2    = (const float*)d_in[1];
  const float* Wq    = (const float*)d_in[2];
  const float* bq    = (const float*)d_in[3];
  const float* Wk    = (const float*)d_in[4];
  const float* bk    = (const float*)d_in[5];
  const float* Wv    = (const float*)d_in[6];
  const float* bv    = (const float*)d_in[7];
  const float* gamma = (const float*)d_in[8];
  const float* beta  = (const float*)d_in[9];
  float* out = (float*)d_out;

  const int LDS_BIG = 131072, LDS_MID = 98304;
  hipFuncSetAttribute((const void*)kv_kernel,
                      hipFuncAttributeMaxDynamicSharedMemorySize, LDS_BIG);
  hipFuncSetAttribute((const void*)scores_kernel,
                      hipFuncAttributeMaxDynamicSharedMemorySize, LDS_BIG);
  hipFuncSetAttribute((const void*)q_kernel,
                      hipFuncAttributeMaxDynamicSharedMemorySize, LDS_MID);
  hipFuncSetAttribute((const void*)pv_kernel,
                      hipFuncAttributeMaxDynamicSharedMemorySize, LDS_MID);

  char* p = (char*)d_ws;
  auto alloc = [&](size_t bytes) -> char* {
    char* r = p;
    p += (bytes + 255) & ~(size_t)255;
    return r;
  };
  u16* x1b   = (u16*)alloc((size_t)CM * CD * 2);
  u16* x2b   = (u16*)alloc((size_t)CM * CD * 2);
  u16* WqT   = (u16*)alloc((size_t)CD * CD * 2);
  u16* WkvT  = (u16*)alloc((size_t)2 * CD * CD * 2);
  u16* Qb    = (u16*)alloc((size_t)CM * CD * 2);
  u16* Kb    = (u16*)alloc((size_t)CM * CD * 2);
  u16* Vt    = (u16*)alloc((size_t)CM * CD * 2);
  u16* Pp    = (u16*)alloc((size_t)CB * CN * CN * 2);
  float* ls  = (float*)alloc((size_t)CB * CN * 4);
  float* vs  = (float*)alloc((size_t)CB * CD * 4);

  hipMemsetAsync(ls, 0, (size_t)CB * CN * 4, stream);
  hipMemsetAsync(vs, 0, (size_t)CB * CD * 4, stream);

  // f32 -> bf16 inputs (one launch)
  {
    dim3 g(CM * CD / 1024, 2);
    cvt_bf16_kernel<<<g, 256, 0, stream>>>(x1, x1b, x2, x2b);
  }

  // W transposes (one launch)
  {
    dim3 g(32, 32, 3), blk(32, 8);
    transpose_w_kernel<<<g, blk, 0, stream>>>(Wq, Wk, Wv, WqT, WkvT);
  }

  // fused K|V projection: K row-major + Vt + vsum (256 blocks)
  {
    dim3 g(32, 8);
    kv_kernel<<<g, 512, LDS_BIG, stream>>>(x2b, WkvT, bk, bv, Kb, Vt, vs);
  }

  // Q projection (256 blocks, 256x128 tiles)
  {
    dim3 g(32, 8);
    q_kernel<<<g, 512, LDS_MID, stream>>>(x1b, WqT, bq, Qb);
  }

  // P = exp(QK^T/32), l = rowsum(P)
  {
    dim3 g(8, 8, CB);
    scores_kernel<<<g, 512, LDS_BIG, stream>>>(Qb, Kb, Pp, ls);
  }

  // out = (vsum - P@V / l) / (N-1)   (256 blocks, 256x128 tiles)
  {
    dim3 g(8, 8, CB);
    pv_kernel<<<g, 512, LDS_MID, stream>>>(Pp, Vt, ls, vs, out);
  }

  // LayerNorm + ReLU in place
  ln_relu_kernel<<<CM, 256, 0, stream>>>(out, gamma, beta);
}